// Round 1
// baseline (721.035 us; speedup 1.0000x reference)
//
#include <hip/hip_runtime.h>

constexpr int BB = 4096;   // batch
constexpr int TT = 2048;   // time
constexpr int HH = 32;     // hidden

typedef float v2f __attribute__((ext_vector_type(2)));
typedef float v4f __attribute__((ext_vector_type(4)));
typedef _Float16 v2h __attribute__((ext_vector_type(2)));
typedef _Float16 v8h __attribute__((ext_vector_type(8)));

// ---------- fast math (v_exp_f32 / v_rcp_f32) ----------
__device__ __forceinline__ float fexp2(float x) { return __builtin_amdgcn_exp2f(x); }
__device__ __forceinline__ float frcp(float x)  { return __builtin_amdgcn_rcpf(x); }
__device__ __forceinline__ float fsigmoid(float x) {
    return frcp(1.0f + fexp2(x * -1.4426950408889634f));
}
__device__ __forceinline__ float felu(float x) {
    return x > 0.0f ? x : (fexp2(x * 1.4426950408889634f) - 1.0f);
}

// ---------- kernel 1: counting sort of batch indices by length, descending ----------
__global__ void sort_by_len_kernel(const int* __restrict__ lengths, int* __restrict__ perm) {
    __shared__ int hist[TT];     // key = TT - len  in [0, TT-1]
    __shared__ int csum[256];
    const int tid = threadIdx.x;
    for (int i = tid; i < TT; i += 256) hist[i] = 0;
    __syncthreads();
    for (int i = tid; i < BB; i += 256) atomicAdd(&hist[TT - lengths[i]], 1);
    __syncthreads();
    const int base = tid * 8;
    int loc[8];
    int s = 0;
#pragma unroll
    for (int j = 0; j < 8; ++j) { loc[j] = hist[base + j]; s += loc[j]; }
    csum[tid] = s;
    __syncthreads();
    for (int off = 1; off < 256; off <<= 1) {
        int v = (tid >= off) ? csum[tid - off] : 0;
        __syncthreads();
        csum[tid] += v;
        __syncthreads();
    }
    int run = csum[tid] - s;
#pragma unroll
    for (int j = 0; j < 8; ++j) { int t = loc[j]; hist[base + j] = run; run += t; }
    __syncthreads();
    for (int i = tid; i < BB; i += 256) {
        int pos = atomicAdd(&hist[TT - lengths[i]], 1);
        perm[pos] = i;
    }
}

// ---------- kernel 2: backward LSTM + MLP head, 2 elements/wave, 1 unit/lane ----------
// Wave layout: lane = e*32 + u  (e = element-in-pair 0/1, u = hidden unit 0..31).
// Each lane owns all FOUR gate rows (i:u, f:32+u, g:64+u, o:96+u) of its element:
//   - c and h update are fully lane-local (no shfl_xor, no cross-lane for the cell)
//   - activations have zero lane waste (all 64 lanes useful every trans instr)
//   - 1 LDS h round-trip serves TWO elements (halved per-element LDS cost)
// Rows pre-scaled by -log2e (sigmoid rows) / -2log2e (tanh row). Fused reciprocals:
//   sig(i)*tanh(g) = (1-Eg) * rcp((1+Ei)(1+Eg))
//   sig(f) = R2*(1+Eo), sig(o) = R2*(1+Ef), R2 = rcp((1+Ef)(1+Eo))
// -> 5 exp2 + 3 rcp per wave-step for 2 element-steps (was 3+3 for 1).
// Pairs are adjacent sorted ranks, so lenA ~= lenB; the shorter element is
// predicated (c/h held) until s < L.
__global__ __attribute__((amdgpu_flat_work_group_size(64, 64)))
void lstm_kernel(const float* __restrict__ x, const int* __restrict__ lengths,
                 const float* __restrict__ w_ih, const float* __restrict__ w_hh,
                 const float* __restrict__ b_ih, const float* __restrict__ b_hh,
                 const float* __restrict__ fc_w, const float* __restrict__ fc_b,
                 const float* __restrict__ fc2_w, const float* __restrict__ fc2_b,
                 float* __restrict__ out, const int* __restrict__ perm) {
    __shared__ __align__(16) _Float16 hlds[64];   // [0..31] = h of elem A, [32..63] = elem B
    __shared__ float xbuf[128];                   // [0..63] = x chunk A, [64..127] = chunk B

    const int lane = threadIdx.x;   // 0..63
    const int u = lane & 31;        // hidden unit
    const int e = lane >> 5;        // element within pair

    const int k0 = 2 * blockIdx.x;
    const int bA = perm ? perm[k0]     : k0;
    const int bB = perm ? perm[k0 + 1] : k0 + 1;
    const int LA = lengths[bA];
    const int LB = lengths[bB];
    const int Lme = e ? LB : LA;          // my element's length (per-lane)
    const int bme = e ? bB : bA;
    const int maxL = LA > LB ? LA : LB;

    const float NL2E  = -1.4426950408889634f;   // -log2(e)   (sigmoid rows)
    const float N2L2E = -2.8853900817779268f;   // -2*log2(e) (tanh rows / tanh(c))

    // per-lane pre-scaled f16 weights: 4 rows x 16 pairs = 64 VGPRs
    v2h wI[16], wF[16], wG[16], wO[16];
    {
        const v2f* pI = reinterpret_cast<const v2f*>(w_hh + (u     ) * 32);
        const v2f* pF = reinterpret_cast<const v2f*>(w_hh + (u + 32) * 32);
        const v2f* pG = reinterpret_cast<const v2f*>(w_hh + (u + 64) * 32);
        const v2f* pO = reinterpret_cast<const v2f*>(w_hh + (u + 96) * 32);
#pragma unroll
        for (int q = 0; q < 16; ++q) {
            v2f ai = pI[q], af = pF[q], ag = pG[q], ao = pO[q];
            wI[q] = (v2h){(_Float16)(ai.x * NL2E),  (_Float16)(ai.y * NL2E)};
            wF[q] = (v2h){(_Float16)(af.x * NL2E),  (_Float16)(af.y * NL2E)};
            wG[q] = (v2h){(_Float16)(ag.x * N2L2E), (_Float16)(ag.y * N2L2E)};
            wO[q] = (v2h){(_Float16)(ao.x * NL2E),  (_Float16)(ao.y * NL2E)};
        }
    }
    const float wiI = w_ih[u     ] * NL2E;
    const float wiF = w_ih[u + 32] * NL2E;
    const float wiG = w_ih[u + 64] * N2L2E;
    const float wiO = w_ih[u + 96] * NL2E;
    const float biI = (b_ih[u     ] + b_hh[u     ]) * NL2E;
    const float biF = (b_ih[u + 32] + b_hh[u + 32]) * NL2E;
    const float biG = (b_ih[u + 64] + b_hh[u + 64]) * N2L2E;
    const float biO = (b_ih[u + 96] + b_hh[u + 96]) * NL2E;

    // anti-remat pin on the weight registers
#pragma unroll
    for (int q = 0; q < 16; ++q) {
        asm volatile("" : "+v"(wI[q]), "+v"(wF[q]), "+v"(wG[q]), "+v"(wO[q]));
    }

    v8h hr[4];
#pragma unroll
    for (int q = 0; q < 4; ++q) hr[q] = (v8h)(_Float16)0.0f;
    float c = 0.0f;

    const float* xA = x + (size_t)bA * TT;
    const float* xB = x + (size_t)bB * TT;
    const float* xme = xbuf + e * 64;
    _Float16* hme = hlds + e * 32;

    int s = maxL - 1;
    while (s >= 0) {
        const int tb = s & ~63;
        // wave-local staging of both elements' x chunks, no barrier needed
        xbuf[lane]      = xA[tb + lane];
        xbuf[64 + lane] = xB[tb + lane];
        for (; s >= tb; --s) {
            const float xt = xme[s - tb];
            // 8 independent dot chains (4 rows x 2 partials), 8-deep each
            float aI0 = fmaf(wiI, xt, biI), aI1 = 0.0f;
            float aF0 = fmaf(wiF, xt, biF), aF1 = 0.0f;
            float aG0 = fmaf(wiG, xt, biG), aG1 = 0.0f;
            float aO0 = fmaf(wiO, xt, biO), aO1 = 0.0f;
#pragma unroll
            for (int q = 0; q < 4; ++q) {
                const v8h hh = hr[q];
                const v2h p0 = __builtin_shufflevector(hh, hh, 0, 1);
                const v2h p1 = __builtin_shufflevector(hh, hh, 2, 3);
                const v2h p2 = __builtin_shufflevector(hh, hh, 4, 5);
                const v2h p3 = __builtin_shufflevector(hh, hh, 6, 7);
                aI0 = __builtin_amdgcn_fdot2(wI[4*q+0], p0, aI0, false);
                aI1 = __builtin_amdgcn_fdot2(wI[4*q+1], p1, aI1, false);
                aI0 = __builtin_amdgcn_fdot2(wI[4*q+2], p2, aI0, false);
                aI1 = __builtin_amdgcn_fdot2(wI[4*q+3], p3, aI1, false);
                aF0 = __builtin_amdgcn_fdot2(wF[4*q+0], p0, aF0, false);
                aF1 = __builtin_amdgcn_fdot2(wF[4*q+1], p1, aF1, false);
                aF0 = __builtin_amdgcn_fdot2(wF[4*q+2], p2, aF0, false);
                aF1 = __builtin_amdgcn_fdot2(wF[4*q+3], p3, aF1, false);
                aG0 = __builtin_amdgcn_fdot2(wG[4*q+0], p0, aG0, false);
                aG1 = __builtin_amdgcn_fdot2(wG[4*q+1], p1, aG1, false);
                aG0 = __builtin_amdgcn_fdot2(wG[4*q+2], p2, aG0, false);
                aG1 = __builtin_amdgcn_fdot2(wG[4*q+3], p3, aG1, false);
                aO0 = __builtin_amdgcn_fdot2(wO[4*q+0], p0, aO0, false);
                aO1 = __builtin_amdgcn_fdot2(wO[4*q+1], p1, aO1, false);
                aO0 = __builtin_amdgcn_fdot2(wO[4*q+2], p2, aO0, false);
                aO1 = __builtin_amdgcn_fdot2(wO[4*q+3], p3, aO1, false);
            }
            // E* = exp2 of pre-scaled gate inputs (e^{-pre} / e^{-2 pre_g})
            const float Ei = fexp2(aI0 + aI1);
            const float Ef = fexp2(aF0 + aF1);
            const float Eg = fexp2(aG0 + aG1);
            const float Eo = fexp2(aO0 + aO1);
            const float Ai = 1.0f + Ei, Ag = 1.0f + Eg;
            const float Af = 1.0f + Ef, Ao = 1.0f + Eo;
            const float R1 = frcp(Ai * Ag);          // fused: sig(i)*tanh(g)
            const float R2 = frcp(Af * Ao);          // fused: sig(f), sig(o)
            const float ig = (1.0f - Eg) * R1;
            const float sf = R2 * Ao;
            const float so = R2 * Af;
            const float cn = fmaf(sf, c, ig);
            const bool act = (s < Lme);              // packed-seq predication
            c = act ? cn : c;
            // tanh(c) = (1-Ec)*rcp(1+Ec), Ec = exp2(-2 log2e * c); clamp avoids
            // (1-inf)*0 = NaN if c ever drifts below ~-44 (cheap insurance)
            const float carg = fminf(c * N2L2E, 126.0f);
            const float Ec = fexp2(carg);
            const float R3 = frcp(1.0f + Ec);
            const float hn = so * ((1.0f - Ec) * R3);
            hme[u] = (_Float16)(act ? hn : 0.0f);
            const v8h* hp = reinterpret_cast<const v8h*>(hme);
#pragma unroll
            for (int q = 0; q < 4; ++q) hr[q] = hp[q];   // 2-addr broadcast reads
        }
    }

    // ---- head: each half handles its element; lane does fc rows u and u+32 ----
    float hf[32];
#pragma unroll
    for (int q = 0; q < 4; ++q) {
        const v8h hh = hr[q];
#pragma unroll
        for (int j = 0; j < 8; ++j) hf[8 * q + j] = (float)hh[j];
    }
    float a0 = fc_b[u], a1 = fc_b[u + 32];
    {
        const v4f* f0 = reinterpret_cast<const v4f*>(fc_w + u * 32);
        const v4f* f1 = reinterpret_cast<const v4f*>(fc_w + (u + 32) * 32);
#pragma unroll
        for (int q = 0; q < 8; ++q) {
            const v4f fa = f0[q];
            const v4f fb = f1[q];
            a0 = fmaf(fa.x, hf[4*q+0], a0); a0 = fmaf(fa.y, hf[4*q+1], a0);
            a0 = fmaf(fa.z, hf[4*q+2], a0); a0 = fmaf(fa.w, hf[4*q+3], a0);
            a1 = fmaf(fb.x, hf[4*q+0], a1); a1 = fmaf(fb.y, hf[4*q+1], a1);
            a1 = fmaf(fb.z, hf[4*q+2], a1); a1 = fmaf(fb.w, hf[4*q+3], a1);
        }
    }
    float partial = felu(a0) * fc2_w[u] + felu(a1) * fc2_w[u + 32];
    // reduce within each 32-lane half (masks < 32 never cross the half boundary)
#pragma unroll
    for (int m = 16; m >= 1; m >>= 1) partial += __shfl_xor(partial, m, 64);
    if (u == 0) out[bme] = fsigmoid(partial + fc2_b[0]);
}

extern "C" void kernel_launch(void* const* d_in, const int* in_sizes, int n_in,
                              void* d_out, int out_size, void* d_ws, size_t ws_size,
                              hipStream_t stream) {
    const float* x       = (const float*)d_in[0];
    const int*   lengths = (const int*)d_in[1];
    const float* w_ih    = (const float*)d_in[2];
    const float* w_hh    = (const float*)d_in[3];
    const float* b_ih    = (const float*)d_in[4];
    const float* b_hh    = (const float*)d_in[5];
    const float* fc_w    = (const float*)d_in[6];
    const float* fc_b    = (const float*)d_in[7];
    const float* fc2_w   = (const float*)d_in[8];
    const float* fc2_b   = (const float*)d_in[9];
    float* out = (float*)d_out;

    int* perm = nullptr;
    if (ws_size >= (size_t)BB * sizeof(int)) {
        perm = (int*)d_ws;
        hipLaunchKernelGGL(sort_by_len_kernel, dim3(1), dim3(256), 0, stream, lengths, perm);
    }
    hipLaunchKernelGGL(lstm_kernel, dim3(BB / 2), dim3(64), 0, stream,
                       x, lengths, w_ih, w_hh, b_ih, b_hh,
                       fc_w, fc_b, fc2_w, fc2_b, out, perm);
}

// Round 2
// 675.886 us; speedup vs baseline: 1.0668x; 1.0668x over previous
//
#include <hip/hip_runtime.h>
#include <hip/hip_bf16.h>

constexpr int BB = 4096;   // batch
constexpr int TT = 2048;   // time
constexpr int HH = 32;     // hidden

typedef float v2f __attribute__((ext_vector_type(2)));
typedef float v4f __attribute__((ext_vector_type(4)));
typedef _Float16 v2h __attribute__((ext_vector_type(2)));
typedef _Float16 v8h __attribute__((ext_vector_type(8)));

// ---------- fast math (v_exp_f32 / v_rcp_f32) ----------
__device__ __forceinline__ float fexp2(float x) { return __builtin_amdgcn_exp2f(x); }
__device__ __forceinline__ float frcp(float x)  { return __builtin_amdgcn_rcpf(x); }
__device__ __forceinline__ float fsigmoid(float x) {
    return frcp(1.0f + fexp2(x * -1.4426950408889634f));
}
__device__ __forceinline__ float felu(float x) {
    return x > 0.0f ? x : (fexp2(x * 1.4426950408889634f) - 1.0f);
}

// ---------- kernel 1: counting sort of batch indices by length, descending ----------
__global__ void sort_by_len_kernel(const int* __restrict__ lengths, int* __restrict__ perm) {
    __shared__ int hist[TT];     // key = TT - len  in [0, TT-1]
    __shared__ int csum[256];
    const int tid = threadIdx.x;
    for (int i = tid; i < TT; i += 256) hist[i] = 0;
    __syncthreads();
    for (int i = tid; i < BB; i += 256) atomicAdd(&hist[TT - lengths[i]], 1);
    __syncthreads();
    const int base = tid * 8;
    int loc[8];
    int s = 0;
#pragma unroll
    for (int j = 0; j < 8; ++j) { loc[j] = hist[base + j]; s += loc[j]; }
    csum[tid] = s;
    __syncthreads();
    for (int off = 1; off < 256; off <<= 1) {
        int v = (tid >= off) ? csum[tid - off] : 0;
        __syncthreads();
        csum[tid] += v;
        __syncthreads();
    }
    int run = csum[tid] - s;
#pragma unroll
    for (int j = 0; j < 8; ++j) { int t = loc[j]; hist[base + j] = run; run += t; }
    __syncthreads();
    for (int i = tid; i < BB; i += 256) {
        int pos = atomicAdd(&hist[TT - lengths[i]], 1);
        perm[pos] = i;
    }
}

// ---------- kernel 2: backward LSTM + MLP head, COMPLEMENT-CHAINED ----------
// Round-0 per-step structure (1 element/wave, 2 gate rows/lane, smallest serial
// chain S ~= 430 cy) + load balancing: wave k processes sorted rank k, then rank
// BB-1-k. Uniform length dist => every wave runs ~L_k + L_{BB-1-k} ~= TT+1 steps.
// 2048 waves = 2 waves/SIMD FLAT for the whole kernel (no occupancy decay, no
// tail): co-wave issue (2*I ~= 420cy) fills the serial-chain stall shadow
// (S ~= 430cy) almost exactly -> VALUBusy ~90%, critical wave barely stretched.
// Gate row ownership (unit n = lane&31):
//   lower lane n    : r0 = n      (i), r1 = 64+n (g)  -> computes ig = sig(i)*tanh(g)
//   upper lane 32+n : r0 = 32+n   (f), r1 = 96+n (o)  -> owns c, computes h
// One __shfl_xor(ig, 32) per step moves ig to the c-owner. Weights are f16
// pairs (32 VGPRs total) consumed by v_dot2_f32_f16 (2 MAC/lane/instr, f32 acc).
// Rows pre-scaled by -log2e (sigmoid) / -2log2e (tanh): act = rcp(1+exp2(g)).
__global__ __attribute__((amdgpu_flat_work_group_size(64, 64), amdgpu_waves_per_eu(1, 4)))
void lstm_kernel(const float* __restrict__ x, const int* __restrict__ lengths,
                 const float* __restrict__ w_ih, const float* __restrict__ w_hh,
                 const float* __restrict__ b_ih, const float* __restrict__ b_hh,
                 const float* __restrict__ fc_w, const float* __restrict__ fc_b,
                 const float* __restrict__ fc2_w, const float* __restrict__ fc2_b,
                 float* __restrict__ out, const int* __restrict__ perm) {
    __shared__ __align__(16) _Float16 hs[64];  // [0..31] junk from lower lanes; [32..63] = h
    __shared__ float xbuf[64];

    const int lane = threadIdx.x;       // 0..63

    const int r0 = lane;        // i (lower) / f (upper)
    const int r1 = lane + 64;   // g (lower) / o (upper)

    const bool  lower  = lane < 32;
    const float NL2E   = -1.4426950408889634f;
    const float scale0 = NL2E;                           // i/f: sigmoid
    const float scale1 = lower ? 2.0f * NL2E : NL2E;     // g: tanh, o: sigmoid
    const float amul   = lower ? 2.0f : 1.0f;
    const float badd   = lower ? -1.0f : 0.0f;

    // per-lane pre-scaled f16 weights in registers (16+16 VGPRs) -- loaded ONCE,
    // shared across both chained elements (weights are element-independent).
    v2h w0[16], w1[16];
    {
        const v2f* p0 = reinterpret_cast<const v2f*>(w_hh + r0 * 32);
        const v2f* p1 = reinterpret_cast<const v2f*>(w_hh + r1 * 32);
#pragma unroll
        for (int q = 0; q < 16; ++q) {
            v2f a = p0[q]; v2f bq = p1[q];
            w0[q] = (v2h){(_Float16)(a.x * scale0), (_Float16)(a.y * scale0)};
            w1[q] = (v2h){(_Float16)(bq.x * scale1), (_Float16)(bq.y * scale1)};
        }
    }
    const float wi0 = w_ih[r0] * scale0;
    const float wi1 = w_ih[r1] * scale1;
    const float bi0 = (b_ih[r0] + b_hh[r0]) * scale0;
    const float bi1 = (b_ih[r1] + b_hh[r1]) * scale1;

    // anti-remat pin (cheap insurance; pressure is low enough to stay in VGPRs)
#pragma unroll
    for (int q = 0; q < 16; ++q) {
        asm volatile("" : "+v"(w0[q]), "+v"(w1[q]));
    }

    for (int phase = 0; phase < 2; ++phase) {
        const int k = phase ? (BB - 1 - (int)blockIdx.x) : (int)blockIdx.x;
        const int b = perm ? perm[k] : k;
        const int L = lengths[b];

        v8h hr[4];
#pragma unroll
        for (int q = 0; q < 4; ++q) hr[q] = (v8h)(_Float16)0.0f;
        float c = 0.0f;
        const float* xb = x + (size_t)b * TT;

        int t = L - 1;
        while (t >= 0) {
            const int tb = t & ~63;
            xbuf[lane] = xb[tb + lane];    // wave-local staging, no barrier needed
            for (; t >= tb; --t) {
                const float xt = xbuf[t - tb];
                float a0  = fmaf(wi0, xt, bi0);
                float a1  = fmaf(wi1, xt, bi1);
                float a0b = 0.0f, a1b = 0.0f;
#pragma unroll
                for (int q = 0; q < 4; ++q) {
                    const v8h hh = hr[q];
                    const v2h p01 = __builtin_shufflevector(hh, hh, 0, 1);
                    const v2h p23 = __builtin_shufflevector(hh, hh, 2, 3);
                    const v2h p45 = __builtin_shufflevector(hh, hh, 4, 5);
                    const v2h p67 = __builtin_shufflevector(hh, hh, 6, 7);
                    a0  = __builtin_amdgcn_fdot2(w0[4*q+0], p01, a0,  false);
                    a0b = __builtin_amdgcn_fdot2(w0[4*q+1], p23, a0b, false);
                    a0  = __builtin_amdgcn_fdot2(w0[4*q+2], p45, a0,  false);
                    a0b = __builtin_amdgcn_fdot2(w0[4*q+3], p67, a0b, false);
                    a1  = __builtin_amdgcn_fdot2(w1[4*q+0], p01, a1,  false);
                    a1b = __builtin_amdgcn_fdot2(w1[4*q+1], p23, a1b, false);
                    a1  = __builtin_amdgcn_fdot2(w1[4*q+2], p45, a1,  false);
                    a1b = __builtin_amdgcn_fdot2(w1[4*q+3], p67, a1b, false);
                }
                const float g0 = a0 + a0b;     // pre-scaled gate inputs
                const float g1 = a1 + a1b;
                const float s0 = frcp(1.0f + fexp2(g0));   // sig(i) / sig(f)
                const float s1 = frcp(1.0f + fexp2(g1));
                const float v1 = fmaf(amul, s1, badd);     // tanh(g) / sig(o)
                const float ig = s0 * v1;                  // lower: i*g (upper: junk)
                const float igx = __shfl_xor(ig, 32);
                // upper lanes own c:  c = f*c + i*g
                c = fmaf(s0, c, igx);
                const float tc = 1.0f - 2.0f * frcp(1.0f + fexp2(c * 2.8853900817779268f));
                const float hn = v1 * tc;                  // upper: sig(o)*tanh(c)
                hs[lane] = (_Float16)hn;                   // real h lands at hs[32..63]
                const v8h* hp = reinterpret_cast<const v8h*>(hs + 32);
#pragma unroll
                for (int q = 0; q < 4; ++q) hr[q] = hp[q]; // broadcast reads
            }
        }

        // ---- head: out[b] = sigmoid( sum_r fc2_w[r]*elu(fc_w[r]@h + fc_b[r]) + fc2_b ) ----
        float hf[32];
#pragma unroll
        for (int q = 0; q < 4; ++q) {
            const v8h hh = hr[q];
#pragma unroll
            for (int j = 0; j < 8; ++j) hf[8 * q + j] = (float)hh[j];
        }
        float a = fc_b[lane];
        {
            const v4f* fp = reinterpret_cast<const v4f*>(fc_w + lane * 32);
#pragma unroll
            for (int q = 0; q < 8; ++q) {
                const v4f f = fp[q];
                a = fmaf(f.x, hf[4 * q + 0], a);
                a = fmaf(f.y, hf[4 * q + 1], a);
                a = fmaf(f.z, hf[4 * q + 2], a);
                a = fmaf(f.w, hf[4 * q + 3], a);
            }
        }
        float partial = felu(a) * fc2_w[lane];
#pragma unroll
        for (int m = 32; m >= 1; m >>= 1) partial += __shfl_xor(partial, m, 64);
        if (lane == 0) out[b] = fsigmoid(partial + fc2_b[0]);
    }
}

extern "C" void kernel_launch(void* const* d_in, const int* in_sizes, int n_in,
                              void* d_out, int out_size, void* d_ws, size_t ws_size,
                              hipStream_t stream) {
    const float* x       = (const float*)d_in[0];
    const int*   lengths = (const int*)d_in[1];
    const float* w_ih    = (const float*)d_in[2];
    const float* w_hh    = (const float*)d_in[3];
    const float* b_ih    = (const float*)d_in[4];
    const float* b_hh    = (const float*)d_in[5];
    const float* fc_w    = (const float*)d_in[6];
    const float* fc_b    = (const float*)d_in[7];
    const float* fc2_w   = (const float*)d_in[8];
    const float* fc2_b   = (const float*)d_in[9];
    float* out = (float*)d_out;

    int* perm = nullptr;
    if (ws_size >= (size_t)BB * sizeof(int)) {
        perm = (int*)d_ws;
        hipLaunchKernelGGL(sort_by_len_kernel, dim3(1), dim3(256), 0, stream, lengths, perm);
    }
    hipLaunchKernelGGL(lstm_kernel, dim3(BB / 2), dim3(64), 0, stream,
                       x, lengths, w_ih, w_hh, b_ih, b_hh,
                       fc_w, fc_b, fc2_w, fc2_b, out, perm);
}